// Round 3
// baseline (54.473 us; speedup 1.0000x reference)
//
#include <hip/hip_runtime.h>
#include <stdint.h>

// Problem constants (fixed by setup_inputs: bs=8, n=4096, c=256, pool=1024)
#define BATCH 8
#define NPTS  4096
#define CH    256
#define QN    1024
#define QPW   4                                  // queries per wave (ILP lever)
#define WAVES_PER_BLOCK 4
#define BLOCK (WAVES_PER_BLOCK * 64)             // 256 threads
#define QPB   (WAVES_PER_BLOCK * QPW)            // 16 queries per block
#define BLOCKS_PER_BATCH (QN / QPB)              // 64
// grid = 8 * 64 = 512 blocks; LDS 64KB -> 2 blocks/CU

__device__ __forceinline__ float fmul(float a, float b) { return __fmul_rn(a, b); }
__device__ __forceinline__ float fadd(float a, float b) { return __fadd_rn(a, b); }

__device__ __forceinline__ void cswap(uint64_t& lo, uint64_t& hi) {
  uint64_t mn = hi < lo ? hi : lo;
  uint64_t mx = hi < lo ? lo : hi;
  lo = mn; hi = mx;
}

// reference-exact distance: ((-2*((xx+yy)+zz_dot)) + q_cand) + q_query, no FMA
__device__ __forceinline__ float cdist(const float4 vq, const float4 v) {
  float dot = fadd(fadd(fmul(vq.x, v.x), fmul(vq.y, v.y)), fmul(vq.z, v.z));
  return fadd(fadd(fmul(-2.0f, dot), v.w), vq.w);
}

// order-preserving float->u32 map, index in low bits -> unique sortable key
__device__ __forceinline__ uint64_t mkkey(float d, int c) {
  uint32_t bb = __float_as_uint(d);
  bb ^= (uint32_t)((int32_t)bb >> 31) | 0x80000000u;
  return ((uint64_t)bb << 32) | (uint32_t)c;
}

// wave-min of u64 key
__device__ __forceinline__ uint64_t wave_min(uint64_t cand) {
#pragma unroll
  for (int s = 32; s >= 1; s >>= 1) {
    uint64_t o = (uint64_t)__shfl_xor((long long)cand, s, 64);
    if (o < cand) cand = o;
  }
  return cand;
}

__shared__ float4 sv[NPTS];   // 64 KB: x,y,z,|v|^2

__global__ __launch_bounds__(BLOCK) void knn_pool_kernel(
    const float* __restrict__ verts,   // [BATCH, NPTS, 3]
    const float* __restrict__ feat,    // [BATCH, NPTS, CH]
    const int*   __restrict__ sidx,    // [QN]
    float* __restrict__ outV,          // [BATCH, QN, 3]
    float* __restrict__ outF)          // [BATCH, QN, CH]
{
  const int batch = blockIdx.x / BLOCKS_PER_BATCH;
  const int qblk  = blockIdx.x % BLOCKS_PER_BATCH;
  const float* vb = verts + (size_t)batch * (NPTS * 3);

  // ---- stage vertices + squared norm into LDS ----
  for (int c = threadIdx.x; c < NPTS; c += BLOCK) {
    float x = vb[c * 3 + 0];
    float y = vb[c * 3 + 1];
    float z = vb[c * 3 + 2];
    float q = fadd(fadd(fmul(x, x), fmul(y, y)), fmul(z, z));
    sv[c] = make_float4(x, y, z, q);
  }
  __syncthreads();

  const int wave = threadIdx.x >> 6;
  const int lane = threadIdx.x & 63;
  const int qbase = qblk * QPB + wave * QPW;     // first of this wave's 4 queries
  const float4* svp = sv + lane;                 // lane-local base

  int   nq[QPW];
  float4 vq[QPW];
#pragma unroll
  for (int q = 0; q < QPW; ++q) {
    nq[q] = sidx[qbase + q];
    vq[q] = sv[nq[q]];                           // broadcast read, conflict-free
  }

  // ---- fast path: per-lane sorted TOP-2 per query (4 independent chains) ----
  uint64_t a0[QPW], a1[QPW];
#pragma unroll
  for (int q = 0; q < QPW; ++q) { a0[q] = ~0ull; a1[q] = ~0ull; }

#pragma unroll 4
  for (int t = 0; t < NPTS / 64; ++t) {
    float4 v = svp[t * 64];
    const int c = lane + t * 64;
#pragma unroll
    for (int q = 0; q < QPW; ++q) {
      uint64_t key = mkkey(cdist(vq[q], v), c);
      a1[q] = key < a1[q] ? key : a1[q];
      cswap(a0[q], a1[q]);
    }
  }

  // ---- per-query wave merge (5 rounds), guard, rare exact fallback ----
  int n1[QPW], n2[QPW], n3[QPW], n4[QPW];
#pragma unroll
  for (int q = 0; q < QPW; ++q) {
    uint64_t prev = 0, nb1 = 0, nb2 = 0, nb3 = 0, nb4 = 0;
#pragma unroll
    for (int r = 0; r < 5; ++r) {
      uint64_t cand = a0[q] > prev ? a0[q] : (a1[q] > prev ? a1[q] : ~0ull);
      cand = wave_min(cand);
      if (r == 1) nb1 = cand;
      if (r == 2) nb2 = cand;
      if (r == 3) nb3 = cand;
      if (r == 4) nb4 = cand;
      prev = cand;
    }
    // exactness guard: any lane may have dropped a key below the merged 5th?
    if (__any(a1[q] < nb4)) {
      // cold path: exact per-lane top-5 rescan for this query
      uint64_t b0 = ~0ull, b1 = ~0ull, b2 = ~0ull, b3 = ~0ull, b4 = ~0ull;
      for (int t = 0; t < NPTS / 64; ++t) {
        float4 v = svp[t * 64];
        uint64_t key = mkkey(cdist(vq[q], v), lane + t * 64);
        b4 = key < b4 ? key : b4;
        cswap(b3, b4); cswap(b2, b3); cswap(b1, b2); cswap(b0, b1);
      }
      prev = 0;
#pragma unroll
      for (int r = 0; r < 5; ++r) {
        uint64_t cand = b0 > prev ? b0
                      : b1 > prev ? b1
                      : b2 > prev ? b2
                      : b3 > prev ? b3
                      : b4 > prev ? b4 : ~0ull;
        cand = wave_min(cand);
        if (r == 1) nb1 = cand;
        if (r == 2) nb2 = cand;
        if (r == 3) nb3 = cand;
        if (r == 4) nb4 = cand;
        prev = cand;
      }
    }
    n1[q] = (int)(uint32_t)nb1;
    n2[q] = (int)(uint32_t)nb2;
    n3[q] = (int)(uint32_t)nb3;
    n4[q] = (int)(uint32_t)nb4;
  }

  // ---- gather 4 feature rows per query, max-pool, store ----
  const float* fb = feat + (size_t)batch * NPTS * CH;
  const int col = lane * 4;   // 64 lanes * 4 = 256 channels
#pragma unroll
  for (int q = 0; q < QPW; ++q) {
    float4 f1 = *(const float4*)(fb + (size_t)n1[q] * CH + col);
    float4 f2 = *(const float4*)(fb + (size_t)n2[q] * CH + col);
    float4 f3 = *(const float4*)(fb + (size_t)n3[q] * CH + col);
    float4 f4 = *(const float4*)(fb + (size_t)n4[q] * CH + col);
    float4 r;
    r.x = fmaxf(fmaxf(f1.x, f2.x), fmaxf(f3.x, f4.x));
    r.y = fmaxf(fmaxf(f1.y, f2.y), fmaxf(f3.y, f4.y));
    r.z = fmaxf(fmaxf(f1.z, f2.z), fmaxf(f3.z, f4.z));
    r.w = fmaxf(fmaxf(f1.w, f2.w), fmaxf(f3.w, f4.w));
    *(float4*)(outF + ((size_t)batch * QN + qbase + q) * CH + col) = r;
  }

  // ---- vertices_pool copy ----
#pragma unroll
  for (int q = 0; q < QPW; ++q) {
    if (lane < 3) {
      float val = lane == 0 ? vq[q].x : (lane == 1 ? vq[q].y : vq[q].z);
      outV[((size_t)batch * QN + qbase + q) * 3 + lane] = val;
    }
  }
}

extern "C" void kernel_launch(void* const* d_in, const int* in_sizes, int n_in,
                              void* d_out, int out_size, void* d_ws, size_t ws_size,
                              hipStream_t stream) {
  const float* verts = (const float*)d_in[0];
  const float* feat  = (const float*)d_in[1];
  const int*   sidx  = (const int*)d_in[2];
  float* outV = (float*)d_out;                          // [BATCH, QN, 3]
  float* outF = (float*)d_out + (size_t)BATCH * QN * 3; // [BATCH, QN, CH]

  dim3 grid(BATCH * BLOCKS_PER_BATCH);   // 512 blocks
  dim3 block(BLOCK);                     // 256 threads (4 waves)
  knn_pool_kernel<<<grid, block, 0, stream>>>(verts, feat, sidx, outV, outF);
}

// Round 4
// 44.579 us; speedup vs baseline: 1.2220x; 1.2220x over previous
//
#include <hip/hip_runtime.h>
#include <stdint.h>

// Problem constants (fixed by setup_inputs: bs=8, n=4096, c=256, pool=1024)
#define BATCH 8
#define NPTS  4096
#define CH    256
#define QN    1024
#define QPW   2                                  // queries per wave
#define WAVES_PER_BLOCK 8
#define BLOCK (WAVES_PER_BLOCK * 64)             // 512 threads
#define QPB   (WAVES_PER_BLOCK * QPW)            // 16 queries per block
#define BLOCKS_PER_BATCH (QN / QPB)              // 64 -> grid 512, 2 blocks/CU

__device__ __forceinline__ float fmul(float a, float b) { return __fmul_rn(a, b); }
__device__ __forceinline__ float fadd(float a, float b) { return __fadd_rn(a, b); }

// reference-exact distance: ((-2*((xx+yy)+zz)) + q_cand) + q_query, no FMA
__device__ __forceinline__ float cdist(const float4 vq, const float4 v) {
  float dot = fadd(fadd(fmul(vq.x, v.x), fmul(vq.y, v.y)), fmul(vq.z, v.z));
  return fadd(fadd(fmul(-2.0f, dot), v.w), vq.w);
}

// order-preserving float->u32 map (with -0.0 canonicalized so that u64 key
// order == (fp compare, then idx) lexicographic order), idx in low bits
__device__ __forceinline__ uint64_t mkkey(float d, uint32_t c) {
  uint32_t bb = __float_as_uint(d);
  if (bb == 0x80000000u) bb = 0u;     // -0.0 -> +0.0
  bb ^= (uint32_t)((int32_t)bb >> 31) | 0x80000000u;
  return ((uint64_t)bb << 32) | c;
}

__device__ __forceinline__ void cswap(uint64_t& lo, uint64_t& hi) {
  uint64_t mn = hi < lo ? hi : lo;
  uint64_t mx = hi < lo ? lo : hi;
  lo = mn; hi = mx;
}

// wave-min of u64: 4 DPP row_ror steps (VALU pipe, 16-lane rows) then
// ^16 / ^32 via shfl (LDS pipe) -- 2 LDS-latency steps instead of 6.
__device__ __forceinline__ uint64_t wave_min(uint64_t x) {
#define DPP_MIN_STEP(CTRL)                                                     \
  {                                                                            \
    uint32_t lo = (uint32_t)x, hi = (uint32_t)(x >> 32);                       \
    uint32_t rl = (uint32_t)__builtin_amdgcn_update_dpp((int)lo, (int)lo,      \
                                                        CTRL, 0xF, 0xF, false);\
    uint32_t rh = (uint32_t)__builtin_amdgcn_update_dpp((int)hi, (int)hi,      \
                                                        CTRL, 0xF, 0xF, false);\
    uint64_t o = ((uint64_t)rh << 32) | rl;                                    \
    x = o < x ? o : x;                                                         \
  }
  DPP_MIN_STEP(0x121)  // row_ror:1
  DPP_MIN_STEP(0x122)  // row_ror:2
  DPP_MIN_STEP(0x124)  // row_ror:4
  DPP_MIN_STEP(0x128)  // row_ror:8
#undef DPP_MIN_STEP
  { uint64_t o = (uint64_t)__shfl_xor((long long)x, 16, 64); x = o < x ? o : x; }
  { uint64_t o = (uint64_t)__shfl_xor((long long)x, 32, 64); x = o < x ? o : x; }
  return x;
}

__shared__ float4 sv[NPTS];   // 64 KB: x,y,z,|v|^2

__global__ __launch_bounds__(BLOCK) void knn_pool_kernel(
    const float* __restrict__ verts,   // [BATCH, NPTS, 3]
    const float* __restrict__ feat,    // [BATCH, NPTS, CH]
    const int*   __restrict__ sidx,    // [QN]
    float* __restrict__ outV,          // [BATCH, QN, 3]
    float* __restrict__ outF)          // [BATCH, QN, CH]
{
  const int batch = blockIdx.x / BLOCKS_PER_BATCH;
  const int qblk  = blockIdx.x % BLOCKS_PER_BATCH;
  const float* vb = verts + (size_t)batch * (NPTS * 3);

  // ---- stage vertices + squared norm into LDS ----
  for (int c = threadIdx.x; c < NPTS; c += BLOCK) {
    float x = vb[c * 3 + 0];
    float y = vb[c * 3 + 1];
    float z = vb[c * 3 + 2];
    float q = fadd(fadd(fmul(x, x), fmul(y, y)), fmul(z, z));
    sv[c] = make_float4(x, y, z, q);
  }
  __syncthreads();

  const int wave = threadIdx.x >> 6;
  const int lane = threadIdx.x & 63;
  const int qbase = qblk * QPB + wave * QPW;
  const float4* svp = sv + lane;

  float4 vq[QPW];
#pragma unroll
  for (int q = 0; q < QPW; ++q) vq[q] = sv[sidx[qbase + q]];   // broadcast

  // ---- scan: per-lane top-2 of (d:f32, idx) per query, strict-< insert ----
  // idx arrives increasing per lane, and strict < keeps the older (smaller
  // idx) on equal d  ->  exactly lexicographic (d, idx) order.
  float    d0[QPW], d1[QPW];
  uint32_t i0[QPW], i1[QPW];
#pragma unroll
  for (int q = 0; q < QPW; ++q) {
    d0[q] = __builtin_inff(); d1[q] = __builtin_inff();
    i0[q] = 0; i1[q] = 0;
  }

#pragma unroll 8
  for (int t = 0; t < NPTS / 64; ++t) {
    float4 v = svp[t * 64];
    const uint32_t c = lane + t * 64;
#pragma unroll
    for (int q = 0; q < QPW; ++q) {
      float d = cdist(vq[q], v);
      bool lt = d < d1[q];
      d1[q] = lt ? d : d1[q];
      i1[q] = lt ? c : i1[q];
      bool sw = d1[q] < d0[q];
      float    td = d0[q];  uint32_t ti = i0[q];
      d0[q] = sw ? d1[q] : d0[q];  i0[q] = sw ? i1[q] : i0[q];
      d1[q] = sw ? td    : d1[q];  i1[q] = sw ? ti    : i1[q];
    }
  }

  // ---- per-query wave merge (5 rounds), guard, rare exact fallback ----
  int n1[QPW], n2[QPW], n3[QPW], n4[QPW];
#pragma unroll
  for (int q = 0; q < QPW; ++q) {
    uint64_t k0 = mkkey(d0[q], i0[q]);
    uint64_t k1 = mkkey(d1[q], i1[q]);
    uint64_t prev = 0, nb1 = 0, nb2 = 0, nb3 = 0, nb4 = 0;
#pragma unroll
    for (int r = 0; r < 5; ++r) {
      uint64_t cand = k0 > prev ? k0 : (k1 > prev ? k1 : ~0ull);
      cand = wave_min(cand);
      if (r == 1) nb1 = cand;
      if (r == 2) nb2 = cand;
      if (r == 3) nb3 = cand;
      if (r == 4) nb4 = cand;
      prev = cand;
    }
    // all per-lane drops are lexicographically > k1; if every lane's k1 >=
    // merged 5th, nothing in the true top-5 was dropped.
    if (__any(k1 < nb4)) {
      // cold path: exact per-lane top-5 rescan for this query
      uint64_t b0 = ~0ull, b1 = ~0ull, b2 = ~0ull, b3 = ~0ull, b4 = ~0ull;
      for (int t = 0; t < NPTS / 64; ++t) {
        float4 v = svp[t * 64];
        uint64_t key = mkkey(cdist(vq[q], v), lane + t * 64);
        b4 = key < b4 ? key : b4;
        cswap(b3, b4); cswap(b2, b3); cswap(b1, b2); cswap(b0, b1);
      }
      prev = 0;
#pragma unroll
      for (int r = 0; r < 5; ++r) {
        uint64_t cand = b0 > prev ? b0
                      : b1 > prev ? b1
                      : b2 > prev ? b2
                      : b3 > prev ? b3
                      : b4 > prev ? b4 : ~0ull;
        cand = wave_min(cand);
        if (r == 1) nb1 = cand;
        if (r == 2) nb2 = cand;
        if (r == 3) nb3 = cand;
        if (r == 4) nb4 = cand;
        prev = cand;
      }
    }
    n1[q] = (int)(uint32_t)nb1;
    n2[q] = (int)(uint32_t)nb2;
    n3[q] = (int)(uint32_t)nb3;
    n4[q] = (int)(uint32_t)nb4;
  }

  // ---- gather 4 feature rows per query, max-pool, store ----
  const float* fb = feat + (size_t)batch * NPTS * CH;
  const int col = lane * 4;   // 64 lanes * 4 = 256 channels
#pragma unroll
  for (int q = 0; q < QPW; ++q) {
    float4 f1 = *(const float4*)(fb + (size_t)n1[q] * CH + col);
    float4 f2 = *(const float4*)(fb + (size_t)n2[q] * CH + col);
    float4 f3 = *(const float4*)(fb + (size_t)n3[q] * CH + col);
    float4 f4 = *(const float4*)(fb + (size_t)n4[q] * CH + col);
    float4 r;
    r.x = fmaxf(fmaxf(f1.x, f2.x), fmaxf(f3.x, f4.x));
    r.y = fmaxf(fmaxf(f1.y, f2.y), fmaxf(f3.y, f4.y));
    r.z = fmaxf(fmaxf(f1.z, f2.z), fmaxf(f3.z, f4.z));
    r.w = fmaxf(fmaxf(f1.w, f2.w), fmaxf(f3.w, f4.w));
    *(float4*)(outF + ((size_t)batch * QN + qbase + q) * CH + col) = r;
  }

  // ---- vertices_pool copy ----
#pragma unroll
  for (int q = 0; q < QPW; ++q) {
    if (lane < 3) {
      float val = lane == 0 ? vq[q].x : (lane == 1 ? vq[q].y : vq[q].z);
      outV[((size_t)batch * QN + qbase + q) * 3 + lane] = val;
    }
  }
}

extern "C" void kernel_launch(void* const* d_in, const int* in_sizes, int n_in,
                              void* d_out, int out_size, void* d_ws, size_t ws_size,
                              hipStream_t stream) {
  const float* verts = (const float*)d_in[0];
  const float* feat  = (const float*)d_in[1];
  const int*   sidx  = (const int*)d_in[2];
  float* outV = (float*)d_out;                          // [BATCH, QN, 3]
  float* outF = (float*)d_out + (size_t)BATCH * QN * 3; // [BATCH, QN, CH]

  dim3 grid(BATCH * BLOCKS_PER_BATCH);   // 512 blocks
  dim3 block(BLOCK);                     // 512 threads (8 waves)
  knn_pool_kernel<<<grid, block, 0, stream>>>(verts, feat, sidx, outV, outF);
}